// Round 3
// baseline (203.653 us; speedup 1.0000x reference)
//
#include <hip/hip_runtime.h>

typedef _Float16 f16;
typedef _Float16 f16x8 __attribute__((ext_vector_type(8)));
typedef float    f32x16 __attribute__((ext_vector_type(16)));

#define NV      2000
#define RR      128
#define KM1     30
#define KKOUT   31
#define NQ      900          // KM1*KM1
#define QQ      961          // KKOUT*KKOUT
#define COV_OFF 62000        // NV*KKOUT

// ws layout:
//   B2  at byte 0        : 30 qt2-tiles x 128 i x 8 s x 1024 B  = 31,457,280 B
//       lane(kq,l31) slot holds B[q=qt2*32+l31][j=s*16+kq*8+d], d=0..7 (f16)
//   Xh  at byte 31457280 : f16 X^T [v=0..2047][r=0..127] = 524,288 B
#define B2_BYTES 31457280

// ---------------------------------------------------------------------------
// Xi (128 x 2000 fp32) -> Xh f16 [v][r], zero-padded v >= 2000.
// ---------------------------------------------------------------------------
__global__ void xcast_kernel(const float* __restrict__ Xi, f16* __restrict__ Xh) {
    int t = blockIdx.x * 256 + threadIdx.x;      // 2048*16 threads
    int v = t & 2047, rc = t >> 11;              // rc 0..15
    f16 vals[8];
#pragma unroll
    for (int d = 0; d < 8; ++d) {
        float x = (v < NV) ? Xi[(rc * 8 + d) * NV + v] : 0.f;
        vals[d] = (f16)x;
    }
    *(uint4*)(Xh + (size_t)v * 128 + rc * 8) = *(uint4*)vals;
}

// ---------------------------------------------------------------------------
// Cov (3840x3840 fp32) -> B2 fragment-tiled f16, one block per Cov row (i,k).
// Phase 1: coalesced float4 stage of the whole row into LDS.
// Phase 2: thread (s,kq,ql) reads 8 LDS floats at stride 30, writes one
// contiguous 16B f16 chunk of B2. q rows 900..959 are never written; the GEMM
// reads 0xAA poison there but discards those outputs (finite f16, harmless).
// ---------------------------------------------------------------------------
__global__ void permute2_kernel(const float* __restrict__ cov, f16* __restrict__ B2) {
    __shared__ float row[3840];
    int blk = blockIdx.x;                        // i*30 + k
    int i = blk / 30, k = blk - i * 30;
    const float4* src4 = (const float4*)(cov + (size_t)blk * 3840);
    for (int t = threadIdx.x; t < 960; t += 512)
        *(float4*)&row[t * 4] = src4[t];
    __syncthreads();
    int t = threadIdx.x;                         // 512
    int s = t >> 6, kq = (t >> 5) & 1, ql = t & 31;
    if (ql >= 30) return;
    int q = 30 * k + ql;
    int qt2 = q >> 5, l31 = q & 31;
    const float* rp = row + (s * 16 + kq * 8) * 30 + ql;
    f16 vals[8];
#pragma unroll
    for (int d = 0; d < 8; ++d) vals[d] = (f16)rp[d * 30];
    f16* dst = B2 + (((size_t)qt2 * 128 + i) * 8 + s) * 512 + kq * 256 + l31 * 8;
    *(uint4*)dst = *(uint4*)vals;
}

// ---------------------------------------------------------------------------
// Zero the whole Post_cov_mats region (1,922,000 floats, /4 exact).
// ---------------------------------------------------------------------------
__global__ void zero_cov_kernel(float* __restrict__ oc) {
    size_t idx = ((size_t)blockIdx.x * 256 + threadIdx.x) * 4;
    if (idx < (size_t)NV * QQ) {
        float4 z = {0.f, 0.f, 0.f, 0.f};
        *(float4*)(oc + idx) = z;
    }
}

// ---------------------------------------------------------------------------
// Post_mean_coefs (2000 x 31) exact fp32; c==0 also plants cov[v,0,0]=0.5
// (runs after zero_cov on the stream).
// ---------------------------------------------------------------------------
__global__ void mean_kernel(const float* __restrict__ Xi,
                            const float* __restrict__ Wm,
                            const float* __restrict__ Cmu,
                            float* __restrict__ outm,
                            float* __restrict__ oc) {
    int tid = blockIdx.x * 256 + threadIdx.x;
    int c = tid >> 11;
    int v = tid & 2047;
    if (v >= NV || c >= KKOUT) return;
    if (c == 0) {
        outm[(size_t)v * KKOUT] = Cmu[v];
        oc[(size_t)v * QQ] = 0.5f;
        return;
    }
    float acc = 0.f;
    const float* w = Wm + (c - 1);
#pragma unroll 8
    for (int i = 0; i < RR; ++i)
        acc = fmaf(Xi[i * NV + v], w[i * KM1], acc);
    outm[(size_t)v * KKOUT + c] = acc;
}

// ---------------------------------------------------------------------------
// GEMM: out(2048 x 960used) = G(2048 x 16384) @ B(16384 x 960), no LDS, no
// barriers. BM=128, BN=64, KZ=4 (32 i-stages per block); 4 waves of 64x32.
// A generated in registers (xj cached whole kernel, xi per 8-stage group);
// B streamed global->reg, fragment-tiled, one-stage-ahead double buffer.
// Grid (15,16,4) = 960 blocks -> ~3.75 blocks/CU resident (96+32 regs = 4/EU
// cap), enough TLP to cover L2 latency. fp32 atomicAdd epilogue (4 partials).
// ---------------------------------------------------------------------------
__launch_bounds__(256, 2)
__global__ void gemm_cov2_kernel(const f16* __restrict__ B2,
                                 const f16* __restrict__ Xh,
                                 float* __restrict__ out_cov) {
    const int q0 = blockIdx.x * 64;              // 0..896
    const int tid  = threadIdx.x;
    const int lane = tid & 63;
    const int wave = tid >> 6;
    const int wm = wave & 1, wn = wave >> 1;
    const int l31 = lane & 31, kq = lane >> 5;
    const int v0 = blockIdx.y * 128;
    const int kz = blockIdx.z;
    const int qt2 = (q0 >> 5) + wn;

    const int vr0 = v0 + wm * 64 + l31;          // fm=0 output row for this lane
    const f16* xrow0 = Xh + (size_t)vr0 * 128;
    const f16* xrow1 = xrow0 + 32 * 128;         // fm=1 row

    // xj[fm][s]: x[v_fm, j], j = s*16 + kq*8 .. +7   (held all kernel: 64 VGPR)
    f16x8 xj[2][8];
#pragma unroll
    for (int s = 0; s < 8; ++s) {
        xj[0][s] = *(const f16x8*)(xrow0 + s * 16 + kq * 8);
        xj[1][s] = *(const f16x8*)(xrow1 + s * 16 + kq * 8);
    }

    const int ibeg = kz * 32;                    // this block's 32 i-stages
    const f16* bptr = B2 + ((size_t)qt2 * 128 + ibeg) * 4096 + lane * 8;

    f32x16 acc[2] = {};
    f16x8 bbuf[2][8];
#pragma unroll
    for (int s = 0; s < 8; ++s)                  // preload stage 0
        bbuf[0][s] = *(const f16x8*)(bptr + s * 512);

    for (int g = 0; g < 4; ++g) {
        f16x8 xi0 = *(const f16x8*)(xrow0 + ibeg + g * 8);
        f16x8 xi1 = *(const f16x8*)(xrow1 + ibeg + g * 8);
#pragma unroll
        for (int t = 0; t < 8; ++t) {
            const int st = g * 8 + t;            // stage 0..31
            const int p  = t & 1;                // bbuf holding stage st
            // prefetch stage st+1 (clamped; independent of compute below)
            const f16* nb = bptr + (size_t)(st < 31 ? st + 1 : 31) * 4096;
#pragma unroll
            for (int s = 0; s < 8; ++s)
                bbuf[p ^ 1][s] = *(const f16x8*)(nb + s * 512);
            // broadcast xi for this stage
            f16 a0 = xi0[t], a1 = xi1[t];
            f16x8 xs0, xs1;
#pragma unroll
            for (int d = 0; d < 8; ++d) { xs0[d] = a0; xs1[d] = a1; }
#pragma unroll
            for (int s = 0; s < 8; ++s) {
                f16x8 af0 = xs0 * xj[0][s];
                f16x8 af1 = xs1 * xj[1][s];
                acc[0] = __builtin_amdgcn_mfma_f32_32x32x16_f16(af0, bbuf[p][s], acc[0], 0, 0, 0);
                acc[1] = __builtin_amdgcn_mfma_f32_32x32x16_f16(af1, bbuf[p][s], acc[1], 0, 0, 0);
            }
        }
    }

    // epilogue: C/D layout col=lane&31 (q), row=4*kq+(reg&3)+8*(reg>>2) (v)
    const int q = q0 + wn * 32 + l31;
    if (q >= NQ) return;
    const int kk = q / 30, ll = q - kk * 30;
    float* cb = out_cov + (kk + 1) * KKOUT + (ll + 1);
#pragma unroll
    for (int fm = 0; fm < 2; ++fm) {
        int vb = v0 + wm * 64 + fm * 32 + 4 * kq;
#pragma unroll
        for (int r = 0; r < 16; ++r) {
            int v = vb + (r & 3) + 8 * (r >> 2);
            if (v < NV) atomicAdd(cb + (size_t)v * QQ, acc[fm][r]);
        }
    }
}

// ---------------------------------------------------------------------------
extern "C" void kernel_launch(void* const* d_in, const int* in_sizes, int n_in,
                              void* d_out, int out_size, void* d_ws, size_t ws_size,
                              hipStream_t stream) {
    const float* Xi  = (const float*)d_in[0];   // (128, 2000)
    const float* Wm  = (const float*)d_in[1];   // (3840, 1)
    const float* Cov = (const float*)d_in[2];   // (3840, 3840)
    const float* Cmu = (const float*)d_in[3];   // (2000, 1)
    float* out      = (float*)d_out;
    float* out_mean = out;                       // (2000, 31)
    float* out_cov  = out + COV_OFF;             // (2000, 31, 31)
    f16* B2 = (f16*)d_ws;
    f16* Xh = (f16*)((char*)d_ws + B2_BYTES);

    xcast_kernel   <<<128, 256, 0, stream>>>(Xi, Xh);
    permute2_kernel<<<3840, 512, 0, stream>>>(Cov, B2);
    zero_cov_kernel<<<((NV * QQ / 4) + 255) / 256, 256, 0, stream>>>(out_cov);
    mean_kernel    <<<(2048 * KKOUT) / 256, 256, 0, stream>>>(Xi, Wm, Cmu, out_mean, out_cov);
    gemm_cov2_kernel<<<dim3(15, 16, 4), 256, 0, stream>>>(B2, Xh, out_cov);
}

// Round 4
// 185.424 us; speedup vs baseline: 1.0983x; 1.0983x over previous
//
#include <hip/hip_runtime.h>

typedef _Float16 f16;
typedef _Float16 f16x8 __attribute__((ext_vector_type(8)));
typedef float    f32x16 __attribute__((ext_vector_type(16)));

#define NV      2000
#define RR      128
#define KM1     30
#define KKOUT   31
#define NQ      900          // KM1*KM1
#define QQ      961          // KKOUT*KKOUT
#define COV_OFF 62000        // NV*KKOUT

// ws layout:
//   B2  at byte 0        : 30 qt-tiles x 128 i x 8 s x 1024 B  = 31,457,280 B
//       lane(kq,l31) slot holds B[q=qt*32+l31][j=s*16+kq*8+d], d=0..7 (f16)
//   Xh  at byte 31457280 : f16 X^T [v=0..2047][r=0..127] = 524,288 B
#define B2_BYTES 31457280

// prep kernel block-role ranges
#define PERM_BLKS  3840
#define XCAST_BLKS 128
#define ZERO_BLKS  1877     // ceil(NV*QQ/4 / 256) = ceil(480500/256)
#define MEAN_BLKS  248      // 2048*31/256
#define PREP_GRID  (PERM_BLKS + XCAST_BLKS + ZERO_BLKS + MEAN_BLKS)

// ---------------------------------------------------------------------------
// Fused prep: one launch does (a) Cov->B2 fragment-tiled f16 permute,
// (b) Xi->Xh f16 cast, (c) zero Post_cov_mats + plant 0.5 at [v,0,0],
// (d) exact fp32 mean. Roles split by blockIdx range; all independent.
// ---------------------------------------------------------------------------
__global__ void prep_kernel(const float* __restrict__ Xi,
                            const float* __restrict__ Wm,
                            const float* __restrict__ cov,
                            const float* __restrict__ Cmu,
                            f16* __restrict__ B2,
                            f16* __restrict__ Xh,
                            float* __restrict__ outm,
                            float* __restrict__ oc) {
    int b = blockIdx.x;
    if (b < PERM_BLKS) {
        // ---- permute: one block per Cov row (i,k) ----
        __shared__ float row[3840];
        int i = b / 30, k = b - i * 30;
        const float4* src4 = (const float4*)(cov + (size_t)b * 3840);
        for (int t = threadIdx.x; t < 960; t += 256)
            *(float4*)&row[t * 4] = src4[t];
        __syncthreads();
#pragma unroll
        for (int it = 0; it < 2; ++it) {
            int t = threadIdx.x + it * 256;      // 0..511
            int s = t >> 6, kq = (t >> 5) & 1, ql = t & 31;
            if (ql < 30) {
                int q = 30 * k + ql;
                int qt = q >> 5, l31 = q & 31;
                const float* rp = row + (s * 16 + kq * 8) * 30 + ql;
                f16 vals[8];
#pragma unroll
                for (int d = 0; d < 8; ++d) vals[d] = (f16)rp[d * 30];
                f16* dst = B2 + (((size_t)qt * 128 + i) * 8 + s) * 512 + kq * 256 + l31 * 8;
                *(uint4*)dst = *(uint4*)vals;
            }
        }
        return;
    }
    b -= PERM_BLKS;
    if (b < XCAST_BLKS) {
        // ---- xcast: Xh[v][r] = f16(Xi[r*NV+v]), zero-pad v>=NV ----
        int t = b * 256 + threadIdx.x;
        int v = t & 2047, rc = t >> 11;          // rc 0..15
        f16 vals[8];
#pragma unroll
        for (int d = 0; d < 8; ++d) {
            float x = (v < NV) ? Xi[(rc * 8 + d) * NV + v] : 0.f;
            vals[d] = (f16)x;
        }
        *(uint4*)(Xh + (size_t)v * 128 + rc * 8) = *(uint4*)vals;
        return;
    }
    b -= XCAST_BLKS;
    if (b < ZERO_BLKS) {
        // ---- zero cov region, planting 0.5 at rem==0 positions ----
        size_t idx = ((size_t)b * 256 + threadIdx.x) * 4;
        if (idx < (size_t)NV * QQ) {
            unsigned rem = (unsigned)(idx % QQ);
            float4 zv;
            zv.x = (rem == 0u)   ? 0.5f : 0.f;
            zv.y = (rem == 960u) ? 0.5f : 0.f;
            zv.z = (rem == 959u) ? 0.5f : 0.f;
            zv.w = (rem == 958u) ? 0.5f : 0.f;
            *(float4*)(oc + idx) = zv;
        }
        return;
    }
    b -= ZERO_BLKS;
    // ---- mean: exact fp32, col 0 = C_mu ----
    int tid = b * 256 + threadIdx.x;
    int c = tid >> 11;
    int v = tid & 2047;
    if (v >= NV || c >= KKOUT) return;
    if (c == 0) { outm[(size_t)v * KKOUT] = Cmu[v]; return; }
    float acc = 0.f;
    const float* w = Wm + (c - 1);
#pragma unroll 8
    for (int i = 0; i < RR; ++i)
        acc = fmaf(Xi[i * NV + v], w[i * KM1], acc);
    outm[(size_t)v * KKOUT + c] = acc;
}

// ---------------------------------------------------------------------------
// GEMM: out(2048 x 960used) = G(2048 x 16384) @ B(16384 x 960), no LDS, no
// barriers. BM=256, BN=32, KZ=2: all 4 waves share one 32-q tile (B frags
// are same-address across waves -> L1 hits), wave index = M-quadrant.
// A generated in registers; B streamed global->reg with 1-stage-ahead dbuf.
// 1-D grid 512, swizzled so the 8 v-blocks sharing a 512KB B-slice land on
// one XCD (ids congruent mod 8) -> slice L2-resident, fetched once.
// fp32 atomicAdd epilogue (2 K-partials per output).
// ---------------------------------------------------------------------------
__launch_bounds__(256, 2)
__global__ void gemm_cov3_kernel(const f16* __restrict__ B2,
                                 const f16* __restrict__ Xh,
                                 float* __restrict__ out_cov) {
    const int bid = blockIdx.x;                  // 0..511
    const int S = ((bid >> 6) << 3) + (bid & 7); // slice 0..63 (qt,z)
    if (S >= 60) return;                         // 32 dead blocks
    const int y  = (bid >> 3) & 7;               // v-block 0..7
    const int z  = S / 30;                       // K-half 0..1
    const int qt = S - z * 30;                   // q-tile 0..29

    const int tid  = threadIdx.x;
    const int lane = tid & 63;
    const int wm   = tid >> 6;                   // M-quadrant 0..3
    const int l31  = lane & 31, kq = lane >> 5;
    const int v0   = y * 256;

    const int vr0 = v0 + wm * 64 + l31;          // fm=0 output row
    const f16* xrow0 = Xh + (size_t)vr0 * 128;
    const f16* xrow1 = xrow0 + 32 * 128;         // fm=1 row

    // xj[fm][s]: x[v_fm, j], j = s*16 + kq*8 .. +7 (held all kernel)
    f16x8 xj[2][8];
#pragma unroll
    for (int s = 0; s < 8; ++s) {
        xj[0][s] = *(const f16x8*)(xrow0 + s * 16 + kq * 8);
        xj[1][s] = *(const f16x8*)(xrow1 + s * 16 + kq * 8);
    }

    const int ibeg = z * 64;                     // this block's 64 i-stages
    const f16* bptr = B2 + ((size_t)qt * 128 + ibeg) * 4096 + lane * 8;

    f32x16 acc[2] = {};
    f16x8 bbuf[2][8];
#pragma unroll
    for (int s = 0; s < 8; ++s)                  // preload stage 0
        bbuf[0][s] = *(const f16x8*)(bptr + s * 512);

    for (int g = 0; g < 8; ++g) {
        f16x8 xi0 = *(const f16x8*)(xrow0 + ibeg + g * 8);
        f16x8 xi1 = *(const f16x8*)(xrow1 + ibeg + g * 8);
#pragma unroll
        for (int t = 0; t < 8; ++t) {
            const int st = g * 8 + t;            // stage 0..63
            const int p  = t & 1;                // bbuf holding stage st
            const f16* nb = bptr + (size_t)(st < 63 ? st + 1 : 63) * 4096;
#pragma unroll
            for (int s = 0; s < 8; ++s)
                bbuf[p ^ 1][s] = *(const f16x8*)(nb + s * 512);
            f16 a0 = xi0[t], a1 = xi1[t];
            f16x8 xs0, xs1;
#pragma unroll
            for (int d = 0; d < 8; ++d) { xs0[d] = a0; xs1[d] = a1; }
#pragma unroll
            for (int s = 0; s < 8; ++s) {
                f16x8 af0 = xs0 * xj[0][s];
                f16x8 af1 = xs1 * xj[1][s];
                acc[0] = __builtin_amdgcn_mfma_f32_32x32x16_f16(af0, bbuf[p][s], acc[0], 0, 0, 0);
                acc[1] = __builtin_amdgcn_mfma_f32_32x32x16_f16(af1, bbuf[p][s], acc[1], 0, 0, 0);
            }
        }
    }

    // epilogue: C/D layout col=lane&31 (q), row=4*kq+(reg&3)+8*(reg>>2) (v)
    const int q = qt * 32 + l31;
    if (q >= NQ) return;
    const int kk = q / 30, ll = q - kk * 30;
    float* cb = out_cov + (kk + 1) * KKOUT + (ll + 1);
#pragma unroll
    for (int fm = 0; fm < 2; ++fm) {
        int vb = v0 + wm * 64 + fm * 32 + 4 * kq;
#pragma unroll
        for (int r = 0; r < 16; ++r) {
            int v = vb + (r & 3) + 8 * (r >> 2);
            if (v < NV) atomicAdd(cb + (size_t)v * QQ, acc[fm][r]);
        }
    }
}

// ---------------------------------------------------------------------------
extern "C" void kernel_launch(void* const* d_in, const int* in_sizes, int n_in,
                              void* d_out, int out_size, void* d_ws, size_t ws_size,
                              hipStream_t stream) {
    const float* Xi  = (const float*)d_in[0];   // (128, 2000)
    const float* Wm  = (const float*)d_in[1];   // (3840, 1)
    const float* Cov = (const float*)d_in[2];   // (3840, 3840)
    const float* Cmu = (const float*)d_in[3];   // (2000, 1)
    float* out      = (float*)d_out;
    float* out_mean = out;                       // (2000, 31)
    float* out_cov  = out + COV_OFF;             // (2000, 31, 31)
    f16* B2 = (f16*)d_ws;
    f16* Xh = (f16*)((char*)d_ws + B2_BYTES);

    prep_kernel     <<<PREP_GRID, 256, 0, stream>>>(Xi, Wm, Cov, Cmu, B2, Xh, out_mean, out_cov);
    gemm_cov3_kernel<<<512, 256, 0, stream>>>(B2, Xh, out_cov);
}